// Round 15
// baseline (151.651 us; speedup 1.0000x reference)
//
#include <hip/hip_runtime.h>
#include <cstdint>

#define T_  2048
#define D_  64
#define BH_ 32
#define W_  256
#define GP  72   // LDS row pitch in shorts (144 B)

typedef float f32x4 __attribute__((ext_vector_type(4)));
using bf16x8 = __attribute__((ext_vector_type(8))) short;   // 8 bf16 in 4 VGPRs

__device__ inline unsigned short f2bf(float x) {            // RNE fp32->bf16
  unsigned u = __float_as_uint(x);
  u = (u + 0x7fffu + ((u >> 16) & 1u)) >> 16;
  return (unsigned short)u;
}

__device__ inline bf16x8 cvt8(const f32x4 lo, const f32x4 hi) {
  bf16x8 r;
  r[0] = (short)f2bf(lo.x); r[1] = (short)f2bf(lo.y);
  r[2] = (short)f2bf(lo.z); r[3] = (short)f2bf(lo.w);
  r[4] = (short)f2bf(hi.x); r[5] = (short)f2bf(hi.y);
  r[6] = (short)f2bf(hi.z); r[7] = (short)f2bf(hi.w);
  return r;
}

// One block (512 thr) per (bh, 128-row strip). Wave-specialized roles:
//  waves 0-3: scan -> gene fitness -> bf16 LDS (wave-private rows), then
//             banded GEMM via swapped-operand mfma_16x16x32_bf16, regular
//             f32x4 stores (L2-merged).
//  waves 4-7: zero streaming of out-of-band segments, rows interleaved mod 4
//             (coherent leapfrog sweep). REGULAR stores this round (round-14
//             isolated variable: NT bypass vs L2-routed write path — the
//             6.7 TB/s fill kernel uses the regular path).
// Separate waves = separate vmcnt, so store backlog never gates band loads.
__global__ __launch_bounds__(512, 4) void fused_strip(const float* __restrict__ pop,
                                                      float* __restrict__ out) {
  __shared__ unsigned short Gs[128 * GP];
  const int unit = blockIdx.x;            // 0..511
  const int i0   = (unit & 15) * 128;
  const int bh   = unit >> 4;
  const int tid  = threadIdx.x;
  const int lane = tid & 63, wv = tid >> 6;   // wv: 0..7
  const float* Pb = pop + (size_t)bh * T_ * D_;
  float*       Ob = out + (size_t)bh * T_ * T_;

  if (wv >= 4) {
    // -------- zero role: rows r == (wv-4) mod 4, coherent leapfrog sweep ----
    const int q = wv - 4;
    int Lz = i0 - 256; if (Lz < 0) Lz = 0;
    const int L4n = Lz >> 2;
    const int R   = i0 + 128;
    const int W4r = (T_ - R) >> 2;
    const f32x4 z4 = {0.f, 0.f, 0.f, 0.f};
    for (int r = q; r < 128; r += 4) {
      float* orow = Ob + (size_t)(i0 + r) * T_;
      f32x4* oL = reinterpret_cast<f32x4*>(orow);
      for (int c = lane; c < L4n; c += 64)
        oL[c] = z4;                       // regular store (L2-routed)
      f32x4* oR = reinterpret_cast<f32x4*>(orow + R);
      for (int c = lane; c < W4r; c += 64)
        oR[c] = z4;                       // regular store (L2-routed)
    }
    return;
  }

  // -------- band role: wave wv owns rows ib0..ib0+31 --------
  const int l15 = lane & 15, l4 = lane >> 4;
  const int ib0 = i0 + wv * 32;

  // ---- scan (chunked, register-lean): rows ib0..ib0+31 -> Gs (bf16) ----
  {
    const int d = lane;                   // lane == feature dim
    const float* P = Pb + d;

    int s0 = ib0 - (W_ - 1); if (s0 < 0) s0 = 0;
    const int jend = ib0 + 1;
    float p0=0.f,p1=0.f,p2=0.f,p3=0.f,p4=0.f,p5=0.f,p6=0.f,p7=0.f;
    int j = s0;
    for (; j + 8 <= jend; j += 8) {
      p0 += P[(size_t)(j+0)*D_]; p1 += P[(size_t)(j+1)*D_];
      p2 += P[(size_t)(j+2)*D_]; p3 += P[(size_t)(j+3)*D_];
      p4 += P[(size_t)(j+4)*D_]; p5 += P[(size_t)(j+5)*D_];
      p6 += P[(size_t)(j+6)*D_]; p7 += P[(size_t)(j+7)*D_];
    }
    for (; j < jend; ++j) p0 += P[(size_t)j*D_];
    float run = ((p0+p1)+(p2+p3)) + ((p4+p5)+(p6+p7));   // window sum @ row ib0

    #pragma unroll
    for (int c = 0; c < 4; ++c) {         // 4 chunks x 8 rows
      float av[8], dv[8];
      #pragma unroll
      for (int k = 0; k < 8; ++k) {
        const int r = c * 8 + k;
        av[k] = (r == 0) ? 0.f : P[(size_t)(ib0 + r) * D_];
        const int jd = ib0 + r - W_;
        dv[k] = (r == 0 || jd < 0) ? 0.f : P[(size_t)jd * D_];
      }
      float rinv[8], sv[8];
      #pragma unroll
      for (int k = 0; k < 8; ++k) {
        run += av[k] - dv[k];
        const int i = ib0 + c * 8 + k;
        const float cnt = (i + 1 < W_) ? (float)(i + 1) : (float)W_;
        rinv[k] = 1.0f / (run / cnt + 0.5f);
        sv[k] = rinv[k];
      }
      #pragma unroll
      for (int m = 32; m >= 1; m >>= 1) {
        #pragma unroll
        for (int k = 0; k < 8; ++k) sv[k] += __shfl_xor(sv[k], m);
      }
      #pragma unroll
      for (int k = 0; k < 8; ++k) {
        const int i = ib0 + c * 8 + k;
        const float cnt = (i + 1 < W_) ? (float)(i + 1) : (float)W_;
        float rowsum = cnt * (64.0f / sv[k] - 0.5f);
        rowsum = fmaxf(rowsum, 1e-10f);
        Gs[(wv * 32 + c * 8 + k) * GP + d] = f2bf(rinv[k] / (rowsum * sv[k]));
      }
    }
  }
  // intra-wave LDS write->read ordering handled by compiler lgkmcnt waits

  // ---- band MFMA: gfs fragments from this wave's own Gs rows ----
  const bf16x8 g00 = *reinterpret_cast<const bf16x8*>(&Gs[(wv*32      + l15) * GP      + l4*8]);
  const bf16x8 g01 = *reinterpret_cast<const bf16x8*>(&Gs[(wv*32      + l15) * GP + 32 + l4*8]);
  const bf16x8 g10 = *reinterpret_cast<const bf16x8*>(&Gs[(wv*32 + 16 + l15) * GP      + l4*8]);
  const bf16x8 g11 = *reinterpret_cast<const bf16x8*>(&Gs[(wv*32 + 16 + l15) * GP + 32 + l4*8]);

  for (int jt = 0; jt < 24; ++jt) {
    const int jb = i0 - 256 + jt * 16;
    if (jb < 0) continue;                 // uniform across the wave
    const float* prow = &Pb[(size_t)(jb + l15) * D_];
    const f32x4 q0 = *reinterpret_cast<const f32x4*>(prow + l4*8);
    const f32x4 q1 = *reinterpret_cast<const f32x4*>(prow + l4*8 + 4);
    const f32x4 q2 = *reinterpret_cast<const f32x4*>(prow + 32 + l4*8);
    const f32x4 q3 = *reinterpret_cast<const f32x4*>(prow + 32 + l4*8 + 4);
    const bf16x8 p0 = cvt8(q0, q1);       // k = l4*8 .. +7
    const bf16x8 p1 = cvt8(q2, q3);       // k = 32 + l4*8 .. +7

    f32x4 c0 = {0.f, 0.f, 0.f, 0.f};
    f32x4 c1 = {0.f, 0.f, 0.f, 0.f};
    c0 = __builtin_amdgcn_mfma_f32_16x16x32_bf16(p0, g00, c0, 0, 0, 0);
    c0 = __builtin_amdgcn_mfma_f32_16x16x32_bf16(p1, g01, c0, 0, 0, 0);
    c1 = __builtin_amdgcn_mfma_f32_16x16x32_bf16(p0, g10, c1, 0, 0, 0);
    c1 = __builtin_amdgcn_mfma_f32_16x16x32_bf16(p1, g11, c1, 0, 0, 0);

    const int jq = jb + l4 * 4;           // 4 consecutive out-cols per lane
    {
      const int i = ib0 + l15;
      f32x4 v;
      #pragma unroll
      for (int r = 0; r < 4; ++r)
        v[r] = ((unsigned)(i - (jq + r)) < 256u) ? c0[r] : 0.f;
      *reinterpret_cast<f32x4*>(&Ob[(size_t)i * T_ + jq]) = v;   // regular: L2 merges
    }
    {
      const int i = ib0 + 16 + l15;
      f32x4 v;
      #pragma unroll
      for (int r = 0; r < 4; ++r)
        v[r] = ((unsigned)(i - (jq + r)) < 256u) ? c1[r] : 0.f;
      *reinterpret_cast<f32x4*>(&Ob[(size_t)i * T_ + jq]) = v;
    }
  }
}

extern "C" void kernel_launch(void* const* d_in, const int* in_sizes, int n_in,
                              void* d_out, int out_size, void* d_ws, size_t ws_size,
                              hipStream_t stream) {
  const float* pop = (const float*)d_in[0];
  float* out = (float*)d_out;
  dim3 blk(512);
  hipLaunchKernelGGL(fused_strip, dim3(16 * BH_), blk, 0, stream, pop, out);
}

// Round 16
// 127.009 us; speedup vs baseline: 1.1940x; 1.1940x over previous
//
#include <hip/hip_runtime.h>
#include <cstdint>

#define T_  2048
#define D_  64
#define BH_ 32
#define W_  256
#define GP  72    // Gs row pitch in shorts (144 B)
#define SP  100   // Stg row pitch in floats (400 B): 16B chunks spread evenly over super-banks

typedef float f32x4 __attribute__((ext_vector_type(4)));
using bf16x8 = __attribute__((ext_vector_type(8))) short;   // 8 bf16 in 4 VGPRs

__device__ inline unsigned short f2bf(float x) {            // RNE fp32->bf16
  unsigned u = __float_as_uint(x);
  u = (u + 0x7fffu + ((u >> 16) & 1u)) >> 16;
  return (unsigned short)u;
}

__device__ inline bf16x8 cvt8(const f32x4 lo, const f32x4 hi) {
  bf16x8 r;
  r[0] = (short)f2bf(lo.x); r[1] = (short)f2bf(lo.y);
  r[2] = (short)f2bf(lo.z); r[3] = (short)f2bf(lo.w);
  r[4] = (short)f2bf(hi.x); r[5] = (short)f2bf(hi.y);
  r[6] = (short)f2bf(hi.z); r[7] = (short)f2bf(hi.w);
  return r;
}

// One block (512 thr) per (bh, 128-row strip). Wave-specialized roles:
//  waves 0-3 (band): scan -> gene fitness -> bf16 LDS (wave-private rows), then
//    banded MFMA in jt-quarters: masked results staged in wave-private LDS tile,
//    then burst NT row-contiguous stores (384B runs per row, monotone in j) --
//    no 16-scattered-page store instructions, no L2 write allocation.
//  waves 4-7 (zero): NT zero streaming, rows interleaved mod 4 (leapfrog sweep).
// All output writes are non-temporal: round-15 A/B showed L2-routed bulk writes
// thrash L2 against pop reads (115 -> 152 us).
__global__ __launch_bounds__(512, 4) void fused_strip(const float* __restrict__ pop,
                                                      float* __restrict__ out) {
  __shared__ unsigned short Gs[128 * GP];      // 18.4 KB
  __shared__ float Stg[4][32 * SP];            // 51.2 KB (12.8 KB per band wave)
  const int unit = blockIdx.x;            // 0..511
  const int i0   = (unit & 15) * 128;
  const int bh   = unit >> 4;
  const int tid  = threadIdx.x;
  const int lane = tid & 63, wv = tid >> 6;   // wv: 0..7
  const float* Pb = pop + (size_t)bh * T_ * D_;
  float*       Ob = out + (size_t)bh * T_ * T_;

  if (wv >= 4) {
    // -------- zero role: rows r == (wv-4) mod 4, NT leapfrog sweep ----------
    const int q = wv - 4;
    int Lz = i0 - 256; if (Lz < 0) Lz = 0;
    const int L4n = Lz >> 2;
    const int R   = i0 + 128;
    const int W4r = (T_ - R) >> 2;
    const f32x4 z4 = {0.f, 0.f, 0.f, 0.f};
    for (int r = q; r < 128; r += 4) {
      float* orow = Ob + (size_t)(i0 + r) * T_;
      f32x4* oL = reinterpret_cast<f32x4*>(orow);
      for (int c = lane; c < L4n; c += 64)
        __builtin_nontemporal_store(z4, &oL[c]);
      f32x4* oR = reinterpret_cast<f32x4*>(orow + R);
      for (int c = lane; c < W4r; c += 64)
        __builtin_nontemporal_store(z4, &oR[c]);
    }
    return;
  }

  // -------- band role: wave wv owns rows ib0..ib0+31 --------
  const int l15 = lane & 15, l4 = lane >> 4;
  const int ib0 = i0 + wv * 32;

  // ---- scan (chunked, register-lean): rows ib0..ib0+31 -> Gs (bf16) ----
  {
    const int d = lane;                   // lane == feature dim
    const float* P = Pb + d;

    int s0 = ib0 - (W_ - 1); if (s0 < 0) s0 = 0;
    const int jend = ib0 + 1;
    float p0=0.f,p1=0.f,p2=0.f,p3=0.f,p4=0.f,p5=0.f,p6=0.f,p7=0.f;
    int j = s0;
    for (; j + 8 <= jend; j += 8) {
      p0 += P[(size_t)(j+0)*D_]; p1 += P[(size_t)(j+1)*D_];
      p2 += P[(size_t)(j+2)*D_]; p3 += P[(size_t)(j+3)*D_];
      p4 += P[(size_t)(j+4)*D_]; p5 += P[(size_t)(j+5)*D_];
      p6 += P[(size_t)(j+6)*D_]; p7 += P[(size_t)(j+7)*D_];
    }
    for (; j < jend; ++j) p0 += P[(size_t)j*D_];
    float run = ((p0+p1)+(p2+p3)) + ((p4+p5)+(p6+p7));   // window sum @ row ib0

    #pragma unroll
    for (int c = 0; c < 4; ++c) {         // 4 chunks x 8 rows
      float av[8], dv[8];
      #pragma unroll
      for (int k = 0; k < 8; ++k) {
        const int r = c * 8 + k;
        av[k] = (r == 0) ? 0.f : P[(size_t)(ib0 + r) * D_];
        const int jd = ib0 + r - W_;
        dv[k] = (r == 0 || jd < 0) ? 0.f : P[(size_t)jd * D_];
      }
      float rinv[8], sv[8];
      #pragma unroll
      for (int k = 0; k < 8; ++k) {
        run += av[k] - dv[k];
        const int i = ib0 + c * 8 + k;
        const float cnt = (i + 1 < W_) ? (float)(i + 1) : (float)W_;
        rinv[k] = 1.0f / (run / cnt + 0.5f);
        sv[k] = rinv[k];
      }
      #pragma unroll
      for (int m = 32; m >= 1; m >>= 1) {
        #pragma unroll
        for (int k = 0; k < 8; ++k) sv[k] += __shfl_xor(sv[k], m);
      }
      #pragma unroll
      for (int k = 0; k < 8; ++k) {
        const int i = ib0 + c * 8 + k;
        const float cnt = (i + 1 < W_) ? (float)(i + 1) : (float)W_;
        float rowsum = cnt * (64.0f / sv[k] - 0.5f);
        rowsum = fmaxf(rowsum, 1e-10f);
        Gs[(wv * 32 + c * 8 + k) * GP + d] = f2bf(rinv[k] / (rowsum * sv[k]));
      }
    }
  }
  // intra-wave LDS write->read ordering handled by compiler lgkmcnt waits

  // ---- band MFMA: gfs fragments from this wave's own Gs rows ----
  const bf16x8 g00 = *reinterpret_cast<const bf16x8*>(&Gs[(wv*32      + l15) * GP      + l4*8]);
  const bf16x8 g01 = *reinterpret_cast<const bf16x8*>(&Gs[(wv*32      + l15) * GP + 32 + l4*8]);
  const bf16x8 g10 = *reinterpret_cast<const bf16x8*>(&Gs[(wv*32 + 16 + l15) * GP      + l4*8]);
  const bf16x8 g11 = *reinterpret_cast<const bf16x8*>(&Gs[(wv*32 + 16 + l15) * GP + 32 + l4*8]);

  float* Sw = &Stg[wv][0];                // wave-private 32 x SP staging tile

  for (int q = 0; q < 4; ++q) {           // jt-quarters: 6 jt = 96 cols each
    const int qcol = i0 - 256 + q * 96;   // quarter's first col (may be < 0)
    if (qcol + 96 <= 0) continue;         // fully clipped

    #pragma unroll
    for (int t = 0; t < 6; ++t) {
      const int jb = qcol + t * 16;
      if (jb < 0) continue;               // uniform across the wave
      const float* prow = &Pb[(size_t)(jb + l15) * D_];
      const f32x4 q0 = *reinterpret_cast<const f32x4*>(prow + l4*8);
      const f32x4 q1 = *reinterpret_cast<const f32x4*>(prow + l4*8 + 4);
      const f32x4 q2 = *reinterpret_cast<const f32x4*>(prow + 32 + l4*8);
      const f32x4 q3 = *reinterpret_cast<const f32x4*>(prow + 32 + l4*8 + 4);
      const bf16x8 p0 = cvt8(q0, q1);     // k = l4*8 .. +7
      const bf16x8 p1 = cvt8(q2, q3);     // k = 32 + l4*8 .. +7

      f32x4 c0 = {0.f, 0.f, 0.f, 0.f};
      f32x4 c1 = {0.f, 0.f, 0.f, 0.f};
      c0 = __builtin_amdgcn_mfma_f32_16x16x32_bf16(p0, g00, c0, 0, 0, 0);
      c0 = __builtin_amdgcn_mfma_f32_16x16x32_bf16(p1, g01, c0, 0, 0, 0);
      c1 = __builtin_amdgcn_mfma_f32_16x16x32_bf16(p0, g10, c1, 0, 0, 0);
      c1 = __builtin_amdgcn_mfma_f32_16x16x32_bf16(p1, g11, c1, 0, 0, 0);

      // mask (causal & window) then stage into wave-private LDS
      const int jq = jb + l4 * 4;         // 4 consecutive out-cols per lane
      f32x4 v0, v1;
      {
        const int i = ib0 + l15;
        #pragma unroll
        for (int r = 0; r < 4; ++r)
          v0[r] = ((unsigned)(i - (jq + r)) < 256u) ? c0[r] : 0.f;
      }
      {
        const int i = ib0 + 16 + l15;
        #pragma unroll
        for (int r = 0; r < 4; ++r)
          v1[r] = ((unsigned)(i - (jq + r)) < 256u) ? c1[r] : 0.f;
      }
      const int sc = t * 16 + l4 * 4;     // col within quarter
      *reinterpret_cast<f32x4*>(&Sw[(l15     ) * SP + sc]) = v0;
      *reinterpret_cast<f32x4*>(&Sw[(l15 + 16) * SP + sc]) = v1;
    }

    // burst: rows ib0..ib0+31, quarter cols, 384B-contiguous per row, NT.
    // 32 rows x 24 quads = 768 lane-elems = 12 iterations of 64 lanes.
    #pragma unroll
    for (int it = 0; it < 12; ++it) {
      const int e  = it * 64 + lane;
      const int r  = e / 24;              // const divisor -> magic mul
      const int qd = e - r * 24;
      const int col = qcol + qd * 4;
      if (col >= 0) {
        const f32x4 v = *reinterpret_cast<const f32x4*>(&Sw[r * SP + qd * 4]);
        __builtin_nontemporal_store(v,
            reinterpret_cast<f32x4*>(&Ob[(size_t)(ib0 + r) * T_ + col]));
      }
    }
  }
}

extern "C" void kernel_launch(void* const* d_in, const int* in_sizes, int n_in,
                              void* d_out, int out_size, void* d_ws, size_t ws_size,
                              hipStream_t stream) {
  const float* pop = (const float*)d_in[0];
  float* out = (float*)d_out;
  dim3 blk(512);
  hipLaunchKernelGGL(fused_strip, dim3(16 * BH_), blk, 0, stream, pop, out);
}